// Round 19
// baseline (407.272 us; speedup 1.0000x reference)
//
#include <hip/hip_runtime.h>
#include <hip/hip_fp16.h>
#include <math.h>

typedef _Float16 h2 __attribute__((ext_vector_type(2)));
typedef _Float16 h8 __attribute__((ext_vector_type(8)));
typedef float f4 __attribute__((ext_vector_type(4)));

#define NWAVES 32768

static __device__ __forceinline__ h2 u2h2(unsigned u) {
    union { unsigned u; h2 h; } x; x.u = u; return x.h;
}

// ---------------------------------------------------------------- CSR build
__global__ __launch_bounds__(256) void count_kernel(const int* __restrict__ dst,
                                                    int* __restrict__ deg, int E) {
    int e = blockIdx.x * 256 + threadIdx.x;
    if (e < E) atomicAdd(&deg[dst[e]], 1);
}

#define SCAN_TPB 256
#define SCAN_VPT 4
#define SCAN_ELEMS (SCAN_TPB * SCAN_VPT)  // 1024

__global__ __launch_bounds__(256) void scan_phase1(const int* __restrict__ deg,
                                                   int* __restrict__ bsum, int n) {
    __shared__ int sh[SCAN_TPB];
    int base = blockIdx.x * SCAN_ELEMS + threadIdx.x * SCAN_VPT;
    int s = 0;
#pragma unroll
    for (int j = 0; j < SCAN_VPT; j++) { int i = base + j; if (i < n) s += deg[i]; }
    sh[threadIdx.x] = s;
    __syncthreads();
    for (int off = 128; off; off >>= 1) {
        if (threadIdx.x < (unsigned)off) sh[threadIdx.x] += sh[threadIdx.x + off];
        __syncthreads();
    }
    if (threadIdx.x == 0) bsum[blockIdx.x] = sh[0];
}

__global__ __launch_bounds__(256) void scan_phase2(int* __restrict__ bsum, int nb,
                                                   int* __restrict__ rowptr, int n) {
    __shared__ int sh[256];
    int v = (threadIdx.x < (unsigned)nb) ? bsum[threadIdx.x] : 0;
    sh[threadIdx.x] = v;
    __syncthreads();
    for (int off = 1; off < 256; off <<= 1) {
        int t = (threadIdx.x >= (unsigned)off) ? sh[threadIdx.x - off] : 0;
        __syncthreads();
        sh[threadIdx.x] += t;
        __syncthreads();
    }
    if (threadIdx.x < (unsigned)nb) bsum[threadIdx.x] = sh[threadIdx.x] - v;  // exclusive
    if (threadIdx.x == 0) rowptr[n] = sh[255];                                // total
}

__global__ __launch_bounds__(256) void scan_phase3(const int* __restrict__ deg,
                                                   const int* __restrict__ bsum,
                                                   int* __restrict__ rowptr,
                                                   int* __restrict__ cursor, int n) {
    __shared__ int sh[SCAN_TPB];
    int tid = threadIdx.x;
    int base = blockIdx.x * SCAN_ELEMS + tid * SCAN_VPT;
    int v[SCAN_VPT];
    int s = 0;
#pragma unroll
    for (int j = 0; j < SCAN_VPT; j++) { int i = base + j; v[j] = (i < n) ? deg[i] : 0; s += v[j]; }
    sh[tid] = s;
    __syncthreads();
    for (int off = 1; off < SCAN_TPB; off <<= 1) {
        int t = (tid >= off) ? sh[tid - off] : 0;
        __syncthreads();
        sh[tid] += t;
        __syncthreads();
    }
    int ex = sh[tid] - s + bsum[blockIdx.x];
#pragma unroll
    for (int j = 0; j < SCAN_VPT; j++) {
        int i = base + j;
        if (i < n) { rowptr[i] = ex; cursor[i] = ex; ex += v[j]; }
    }
}

// CSR record: {src, half2(ea0,ea0), half2(ea1,ea1), half2(ea2,ea2)}
__global__ __launch_bounds__(256) void scatter_kernel(const int* __restrict__ src,
                                                      const int* __restrict__ dst,
                                                      const float* __restrict__ ea,
                                                      int* __restrict__ cursor,
                                                      uint4* __restrict__ csr4, int E) {
    int e = blockIdx.x * 256 + threadIdx.x;
    if (e < E) {
        int d = dst[e];
        int pos = atomicAdd(&cursor[d], 1);
        size_t eb3 = (size_t)e * 3;
        uint4 r;
        r.x = (unsigned)src[e];
        __half2 p0, p1, p2;
        p0.x = p0.y = __float2half_rn(ea[eb3]);
        p1.x = p1.y = __float2half_rn(ea[eb3 + 1]);
        p2.x = p2.y = __float2half_rn(ea[eb3 + 2]);
        r.y = *(unsigned*)&p0; r.z = *(unsigned*)&p1; r.w = *(unsigned*)&p2;
        csr4[pos] = r;
    }
}

// ------------- wave load balance: wstart[q] = first node d whose rowptr[d]
// >= q*E/NWAVES (pure edge balance).
__global__ __launch_bounds__(256) void wbal_kernel(const int* __restrict__ rowptr,
                                                   int Nn, int* __restrict__ wstart) {
    int q = blockIdx.x * 256 + threadIdx.x;
    if (q > NWAVES) return;
    if (q == 0) { wstart[0] = 0; return; }
    if (q == NWAVES) { wstart[NWAVES] = Nn; return; }
    int Etot = rowptr[Nn];
    int t = (int)(((long long)q * Etot) / NWAVES);
    int lo = 0, hi = Nn;
    while (lo < hi) {
        int mid = (lo + hi) >> 1;
        if (rowptr[mid] < t) lo = mid + 1; else hi = mid;
    }
    wstart[q] = lo;
}

// ------------- epilogue constants: A = 0.25*g*rsqrt(v+eps); B = (bias-m)*s+b
__global__ __launch_bounds__(256) void bnprep_kernel(const float* __restrict__ c0,
                                                     const float* __restrict__ cb,   // [3][64]
                                                     const float* __restrict__ bng,
                                                     const float* __restrict__ bnb,
                                                     const float* __restrict__ bnm,
                                                     const float* __restrict__ bnv,
                                                     float* __restrict__ epi) {      // [4][2][64]
    int t = threadIdx.x;           // exactly 256 = 4 layers x 64 channels
    int l = t >> 6, c = t & 63;
    float s = bng[l * 64 + c] * rsqrtf(bnv[l * 64 + c] + 1e-5f);
    float bias = (l == 0) ? c0[c] : cb[(l - 1) * 64 + c];
    epi[l * 128 + c] = 0.25f * s;
    epi[l * 128 + 64 + c] = (bias - bnm[l * 64 + c]) * s + bnb[l * 64 + c];
}

// ------------- group starts from SORTED batch: gstart[g] = first node of g
__global__ __launch_bounds__(256) void gstart_kernel(const int* __restrict__ batch,
                                                     int* __restrict__ gstart,
                                                     int Nn, int Gg) {
    int n = blockIdx.x * 256 + threadIdx.x;
    if (n >= Nn) return;
    int b = batch[n];
    int prev = (n == 0) ? -1 : batch[n - 1];
    for (int g = prev + 1; g <= b; g++) gstart[g] = n;
    if (n == Nn - 1)
        for (int g = b + 1; g <= Gg; g++) gstart[g] = Nn;
}

// ------------- weight prep: pack Wl|Wr (fp16, zero-padded) into MFMA A-frag
__global__ __launch_bounds__(256) void wprep_kernel(const float* __restrict__ W0l,
                                                    const float* __restrict__ W0r,
                                                    const float* __restrict__ Wl,
                                                    const float* __restrict__ Wr,
                                                    __half* __restrict__ Wp) {
    int t = blockIdx.x * 256 + threadIdx.x;   // 4 layers * 4096
    int layer = t >> 12;
    int r = t & 4095;
    int lane = r & 63;
    int ks = (r >> 6) & 1;
    int gct = r >> 7;                          // 0..31
    int K = (layer == 0) ? 9 : 64;
    const float* Wsrc;
    if (layer == 0) Wsrc = (gct < 16) ? W0l : W0r;
    else            Wsrc = ((gct < 16) ? Wl : Wr) + (size_t)(layer - 1) * 64 * 256;
    int cl = ((gct & 15) << 4) + (lane & 15);
    int k0 = (ks << 5) + ((lane >> 4) << 3);
    __half vals[8] __attribute__((aligned(16)));
#pragma unroll
    for (int j = 0; j < 8; j++) {
        int k = k0 + j;
        vals[j] = __float2half_rn((k < K) ? Wsrc[(size_t)k * 256 + cl] : 0.f);
    }
    *(uint4*)(Wp + (size_t)t * 8) = *(const uint4*)vals;
}

// ----------------- MFMA gemm2: xl = fp16(x@Wl+bl), xr = fp16(x@Wr).
template <int K>
__global__ __launch_bounds__(256) void gemm2_mfma_kernel(const float* __restrict__ xin,
                                                         const __half* __restrict__ Wp,
                                                         const float* __restrict__ bl,
                                                         __half* __restrict__ xl,
                                                         __half* __restrict__ xr, int Nn) {
    constexpr int NKS = (K > 32) ? 2 : 1;
    constexpr int KP = NKS * 32;                 // padded K (32 or 64)
    __shared__ __align__(16) float shx[32][KP + 4];
    int tid = threadIdx.x;
    int lane = tid & 63;
    int wv = tid >> 6;           // 0..3
    int nb = blockIdx.x * 32;
    int l15 = lane & 15;
    int lg = lane >> 4;          // 0..3

    // ---- stage B into LDS (coalesced)
    if (K != KP) {
        for (int q = tid; q < 32 * KP; q += 256) shx[q / KP][q % KP] = 0.f;
        __syncthreads();
    }
    if (K == 64) {
        for (int q = tid; q < 32 * 16; q += 256) {   // 512 float4
            int r = q >> 4, c4 = q & 15;
            int node = nb + r;
            float4 v = (node < Nn) ? *(const float4*)(xin + (size_t)node * 64 + c4 * 4)
                                   : make_float4(0.f, 0.f, 0.f, 0.f);
            *(float4*)&shx[r][c4 * 4] = v;
        }
    } else {
        for (int q = tid; q < 32 * K; q += 256) {
            int r = q / K, c = q - r * K;
            int node = nb + r;
            shx[r][c] = (node < Nn) ? xin[(size_t)node * K + c] : 0.f;
        }
    }
    __syncthreads();

    // A fragments (weights), resident: 8 col-tiles x NKS
    h8 afr[8][NKS];
#pragma unroll
    for (int i = 0; i < 8; i++) {
        int gct = wv * 8 + i;
#pragma unroll
        for (int ks = 0; ks < NKS; ks++)
            afr[i][ks] = *(const h8*)(Wp + (((size_t)(gct * 2 + ks)) * 64 + lane) * 8);
    }
    // B fragments from LDS -> fp16
    h8 bfr[2][NKS];
#pragma unroll
    for (int nt = 0; nt < 2; nt++) {
        int row = nt * 16 + l15;
#pragma unroll
        for (int ks = 0; ks < NKS; ks++) {
            int k0 = ks * 32 + lg * 8;
            float4 f0 = *(const float4*)&shx[row][k0];
            float4 f1 = *(const float4*)&shx[row][k0 + 4];
            h8 b;
            b[0] = (_Float16)f0.x; b[1] = (_Float16)f0.y;
            b[2] = (_Float16)f0.z; b[3] = (_Float16)f0.w;
            b[4] = (_Float16)f1.x; b[5] = (_Float16)f1.y;
            b[6] = (_Float16)f1.z; b[7] = (_Float16)f1.w;
            bfr[nt][ks] = b;
        }
    }
    // accumulators, init with bias on the xl side
    f4 acc[8][2];
#pragma unroll
    for (int i = 0; i < 8; i++) {
        int gct = wv * 8 + i;
        f4 ini;
        if (gct < 16) {
            float4 b4 = *(const float4*)(bl + (gct << 4) + (lg << 2));
            ini[0] = b4.x; ini[1] = b4.y; ini[2] = b4.z; ini[3] = b4.w;
        } else {
            ini[0] = 0.f; ini[1] = 0.f; ini[2] = 0.f; ini[3] = 0.f;
        }
        acc[i][0] = ini;
        acc[i][1] = ini;
    }
    // matrix core
#pragma unroll
    for (int i = 0; i < 8; i++)
#pragma unroll
        for (int nt = 0; nt < 2; nt++)
#pragma unroll
            for (int ks = 0; ks < NKS; ks++)
                acc[i][nt] = __builtin_amdgcn_mfma_f32_16x16x32_f16(
                    afr[i][ks], bfr[nt][ks], acc[i][nt], 0, 0, 0);
    // store: 4 consecutive cols per lane -> uint2
#pragma unroll
    for (int i = 0; i < 8; i++) {
        int gct = wv * 8 + i;
        __half* outp = (gct < 16) ? xl : xr;
        int cl = ((gct & 15) << 4) + (lg << 2);
#pragma unroll
        for (int nt = 0; nt < 2; nt++) {
            int node = nb + nt * 16 + l15;
            if (node < Nn) {
                __half h4[4] __attribute__((aligned(8)));
                h4[0] = __float2half_rn(acc[i][nt][0]);
                h4[1] = __float2half_rn(acc[i][nt][1]);
                h4[2] = __float2half_rn(acc[i][nt][2]);
                h4[3] = __float2half_rn(acc[i][nt][3]);
                *(uint2*)(outp + (size_t)node * 256 + cl) = *(const uint2*)h4;
            }
        }
    }
}

// --------------------------- fused GATv2 (R14 structure, unchanged inner
// loop): persistent wave, contiguous node ranges, fp16 packed score path,
// s_load csr4, A/B reg dbuf EB=6. Grid 4x oversubscribed (NWAVES=32768) so
// block-level backfill absorbs the completion-time tail.
#define EB 6

#define GISSUE(S, ibase)                                                               \
    {                                                                                  \
        _Pragma("unroll") for (int j = 0; j < EB; j++) {                               \
            int idx = (ibase) + j;                                                     \
            if (idx < end) {                                                           \
                uint4 ce = csr4[idx]; /* uniform -> s_load_dwordx4 */                  \
                cey##S[j] = ce.y; cez##S[j] = ce.z; cew##S[j] = ce.w;                  \
                int sn = (int)ce.x;                                                    \
                xpk##S[j] = *(const uint2*)(xl + ((size_t)sn << 8) + (lane << 2));     \
            } else {                                                                   \
                cey##S[j] = 0u; cez##S[j] = 0u; cew##S[j] = 0u;                        \
                xpk##S[j] = make_uint2(0u, 0u);                                        \
            }                                                                          \
        }                                                                              \
    }

#define GCOMPUTE(S, ibase)                                                             \
    {                                                                                  \
        float p[EB];                                                                   \
        _Pragma("unroll") for (int j = 0; j < EB; j++) {                               \
            int idx = (ibase) + j;                                                     \
            if (idx < end) {                                                           \
                h2 ea0 = u2h2(cey##S[j]);                                              \
                h2 ea1 = u2h2(cez##S[j]);                                              \
                h2 ea2 = u2h2(cew##S[j]);                                              \
                h2 xl01 = u2h2(xpk##S[j].x);                                           \
                h2 xl23 = u2h2(xpk##S[j].y);                                           \
                h2 t01 = __builtin_elementwise_fma(ea0, we0a,                          \
                           __builtin_elementwise_fma(ea1, we1a,                        \
                             __builtin_elementwise_fma(ea2, we2a, xr01))) + xl01;      \
                h2 t23 = __builtin_elementwise_fma(ea0, we0b,                          \
                           __builtin_elementwise_fma(ea1, we1b,                        \
                             __builtin_elementwise_fma(ea2, we2b, xr23))) + xl23;      \
                h2 l01 = __builtin_elementwise_max(t01, t01 * c02);                    \
                h2 l23 = __builtin_elementwise_max(t23, t23 * c02);                    \
                p[j] = __builtin_amdgcn_fdot2(l01, atta,                               \
                           __builtin_amdgcn_fdot2(l23, attb, 0.f, false), false);      \
            } else p[j] = -INFINITY;                                                   \
        }                                                                              \
        _Pragma("unroll") for (int off = 1; off < 16; off <<= 1) {                     \
            _Pragma("unroll") for (int j = 0; j < EB; j++) p[j] += __shfl_xor(p[j], off); \
        }                                                                              \
        _Pragma("unroll") for (int j = 0; j < EB; j++) {                               \
            float wv2 = __expf(p[j]);                                                  \
            float2 f0 = __half22float2(*(const __half2*)&xpk##S[j].x);                 \
            float2 f1 = __half22float2(*(const __half2*)&xpk##S[j].y);                 \
            f4 xf; xf[0] = f0.x; xf[1] = f0.y; xf[2] = f1.x; xf[3] = f1.y;             \
            acc = acc + wv2 * xf;                                                      \
            l_run += wv2;                                                              \
        }                                                                              \
    }

__global__ __launch_bounds__(256) void gat_kernel(const __half* __restrict__ xl,
                                                  const __half* __restrict__ xr,
                                                  const float* __restrict__ We,   // [3,256]
                                                  const float* __restrict__ att,  // [256]
                                                  const float* __restrict__ epi,  // [2][64]
                                                  const int* __restrict__ rowptr,
                                                  const int* __restrict__ wstart,
                                                  const uint4* __restrict__ csr4,
                                                  float* __restrict__ hout,       // [N,64]
                                                  const float* __restrict__ hres, // [N,64] or null
                                                  int Nn) {
    int tid = threadIdx.x;
    int lane = tid & 63;
    int w = __builtin_amdgcn_readfirstlane(tid >> 6);
    int wave = blockIdx.x * 4 + w;

    // fp16 constants (per-lane)
    float4 we0f = *(const float4*)&We[lane * 4];
    float4 we1f = *(const float4*)&We[256 + lane * 4];
    float4 we2f = *(const float4*)&We[512 + lane * 4];
    float4 attf = *(const float4*)&att[lane * 4];
    h2 we0a = { (_Float16)we0f.x, (_Float16)we0f.y };
    h2 we0b = { (_Float16)we0f.z, (_Float16)we0f.w };
    h2 we1a = { (_Float16)we1f.x, (_Float16)we1f.y };
    h2 we1b = { (_Float16)we1f.z, (_Float16)we1f.w };
    h2 we2a = { (_Float16)we2f.x, (_Float16)we2f.y };
    h2 we2b = { (_Float16)we2f.z, (_Float16)we2f.w };
    h2 atta = { (_Float16)attf.x, (_Float16)attf.y };
    h2 attb = { (_Float16)attf.z, (_Float16)attf.w };
    h2 c02 = { (_Float16)0.2f, (_Float16)0.2f };
    float4 eA = *(const float4*)&epi[(lane & 15) * 4];
    float4 eB4 = *(const float4*)&epi[64 + (lane & 15) * 4];

    int ns = wstart[wave], ne = wstart[wave + 1];
    int d = ns;
    if (d >= ne) return;
    int beg = rowptr[d];            // scalar loads, sequential stream
    int end = rowptr[d + 1];
    uint2 xrp = *(const uint2*)(xr + ((size_t)d << 8) + (lane << 2));

    uint2 xpkA[EB], xpkB[EB];
    unsigned ceyA[EB], cezA[EB], cewA[EB], ceyB[EB], cezB[EB], cewB[EB];

    while (d < ne) {
        // ---- prefetch next node's meta (SGPR + 2 VGPR), consumed at roll
        int dn = d + 1;
        int begn = 0, endn = 0;
        uint2 xrpn = make_uint2(0u, 0u);
        if (dn < ne) {
            begn = rowptr[dn];
            endn = rowptr[dn + 1];
            xrpn = *(const uint2*)(xr + ((size_t)dn << 8) + (lane << 2));
        }
        // ---- current node
        h2 xr01 = u2h2(xrp.x);
        h2 xr23 = u2h2(xrp.y);

        float l_run = 0.f;
        f4 acc; acc[0] = 0.f; acc[1] = 0.f; acc[2] = 0.f; acc[3] = 0.f;

        int i = beg;
        if (i < end) {
            GISSUE(A, i);
            for (;;) {
                int nx = i + EB;
                if (nx < end) GISSUE(B, nx);
                GCOMPUTE(A, i);
                i = nx;
                if (i >= end) break;
                nx = i + EB;
                if (nx < end) GISSUE(A, nx);
                GCOMPUTE(B, i);
                i = nx;
                if (i >= end) break;
            }
        }
        // ---- epilogue: head-mean + BN/bias (precomputed) + ELU + residual
        float inv = (end > beg) ? 1.f / l_run : 0.f;
        float4 o = make_float4(acc[0] * inv, acc[1] * inv, acc[2] * inv, acc[3] * inv);
#pragma unroll
        for (int off = 16; off < 64; off <<= 1) {
            o.x += __shfl_xor(o.x, off);
            o.y += __shfl_xor(o.y, off);
            o.z += __shfl_xor(o.z, off);
            o.w += __shfl_xor(o.w, off);
        }
        if (lane < 16) {
            float vx = fmaf(o.x, eA.x, eB4.x);
            float vy = fmaf(o.y, eA.y, eB4.y);
            float vz = fmaf(o.z, eA.z, eB4.z);
            float vw = fmaf(o.w, eA.w, eB4.w);
            vx = vx > 0.f ? vx : expm1f(vx);
            vy = vy > 0.f ? vy : expm1f(vy);
            vz = vz > 0.f ? vz : expm1f(vz);
            vw = vw > 0.f ? vw : expm1f(vw);
            if (hres) {
                float4 r4 = *(const float4*)&hres[((size_t)d << 6) + (lane << 2)];
                vx += r4.x; vy += r4.y; vz += r4.z; vw += r4.w;
            }
            *(float4*)&hout[((size_t)d << 6) + (lane << 2)] = make_float4(vx, vy, vz, vw);
        }
        // ---- roll to prefetched node
        d = dn; beg = begn; end = endn; xrp = xrpn;
    }
}

// -------------------- pooling + MLP head fused (batch sorted, no atomics)
__global__ __launch_bounds__(256) void poolhead_kernel(const float* __restrict__ h,
                                                       const int* __restrict__ gstart,
                                                       const float* __restrict__ Wo1,
                                                       const float* __restrict__ bo1,
                                                       const float* __restrict__ Wo2,
                                                       const float* __restrict__ bo2,
                                                       float* __restrict__ out, int Gg) {
    __shared__ float red[4][64];
    __shared__ float sp[64];
    int g = blockIdx.x;
    int tid = threadIdx.x;
    int lane = tid & 63, w = tid >> 6;
    int gs = gstart[g], ge = gstart[g + 1];
    float s = 0.f;
    for (int n = gs + w; n < ge; n += 4) s += h[((size_t)n << 6) + lane];
    red[w][lane] = s;
    __syncthreads();
    if (tid < 64) {
        float tot = red[0][tid] + red[1][tid] + red[2][tid] + red[3][tid];
        float c = fmaxf((float)(ge - gs), 1.f);
        sp[tid] = tot / c;
    }
    __syncthreads();
    if (tid < 64) {
        float hid = 0.f;
        if (tid < 32) {
            hid = bo1[tid];
            for (int k = 0; k < 64; k++) hid += sp[k] * Wo1[k * 32 + tid];
            hid = hid > 0.f ? hid : expm1f(hid);
            hid *= Wo2[tid];
        }
#pragma unroll
        for (int off = 32; off; off >>= 1) hid += __shfl_xor(hid, off);
        if (tid == 0) out[g] = hid + bo2[0];
    }
}

extern "C" void kernel_launch(void* const* d_in, const int* in_sizes, int n_in,
                              void* d_out, int out_size, void* d_ws, size_t ws_size,
                              hipStream_t stream) {
    const float* x   = (const float*)d_in[0];
    const int*   ei  = (const int*)d_in[1];
    const int*   bat = (const int*)d_in[2];
    const float* ea  = (const float*)d_in[3];
    const float* W0l = (const float*)d_in[4];
    const float* b0l = (const float*)d_in[5];
    const float* W0r = (const float*)d_in[6];
    const float* W0e = (const float*)d_in[7];
    const float* a0  = (const float*)d_in[8];
    const float* c0  = (const float*)d_in[9];
    const float* Wl  = (const float*)d_in[10];
    const float* bl  = (const float*)d_in[11];
    const float* Wr  = (const float*)d_in[12];
    const float* We  = (const float*)d_in[13];
    const float* a   = (const float*)d_in[14];
    const float* cb  = (const float*)d_in[15];
    const float* bng = (const float*)d_in[16];
    const float* bnb = (const float*)d_in[17];
    const float* bnm = (const float*)d_in[18];
    const float* bnv = (const float*)d_in[19];
    const float* Wo1 = (const float*)d_in[20];
    const float* bo1 = (const float*)d_in[21];
    const float* Wo2 = (const float*)d_in[22];
    const float* bo2 = (const float*)d_in[23];

    int Nn = in_sizes[2];
    int Ee = in_sizes[1] / 2;
    int Gg = out_size;
    const int* srcv = ei;
    const int* dstv = ei + Ee;

    char* w = (char*)d_ws;
    auto alloc = [&](size_t bytes) {
        char* p = w;
        w += (bytes + 255) & ~(size_t)255;
        return p;
    };
    __half* xlb    = (__half*)alloc((size_t)Nn * 256 * 2);
    __half* xrb    = (__half*)alloc((size_t)Nn * 256 * 2);
    float*  hbuf   = (float*)alloc((size_t)Nn * 64 * 4);
    int*    deg    = (int*)alloc((size_t)Nn * 4);
    int*    rowptr = (int*)alloc((size_t)(Nn + 1) * 4);
    int*    cursor = (int*)alloc((size_t)Nn * 4);
    uint4*  csr4   = (uint4*)alloc((size_t)(Ee + 64) * 16);
    int*    gstart = (int*)alloc((size_t)(Gg + 1) * 4);
    int*    wstart = (int*)alloc((size_t)(NWAVES + 1) * 4);
    int*    bsum   = (int*)alloc(256 * 4);
    float*  epi    = (float*)alloc(4 * 128 * 4);
    __half* Wp     = (__half*)alloc((size_t)4 * 32768 * 2);

    int nscan = (Nn + SCAN_ELEMS - 1) / SCAN_ELEMS;  // <=256 for Nn<=262144

    // CSR build + balance + weight/epilogue prep + group starts
    hipMemsetAsync(deg, 0, (size_t)Nn * 4, stream);
    count_kernel<<<(Ee + 255) / 256, 256, 0, stream>>>(dstv, deg, Ee);
    scan_phase1<<<nscan, 256, 0, stream>>>(deg, bsum, Nn);
    scan_phase2<<<1, 256, 0, stream>>>(bsum, nscan, rowptr, Nn);
    scan_phase3<<<nscan, 256, 0, stream>>>(deg, bsum, rowptr, cursor, Nn);
    scatter_kernel<<<(Ee + 255) / 256, 256, 0, stream>>>(srcv, dstv, ea, cursor, csr4, Ee);
    wbal_kernel<<<(NWAVES + 256) / 256, 256, 0, stream>>>(rowptr, Nn, wstart);
    bnprep_kernel<<<1, 256, 0, stream>>>(c0, cb, bng, bnb, bnm, bnv, epi);
    wprep_kernel<<<64, 256, 0, stream>>>(W0l, W0r, Wl, Wr, Wp);
    gstart_kernel<<<(Nn + 255) / 256, 256, 0, stream>>>(bat, gstart, Nn, Gg);

    int gatg = NWAVES / 4;   // 8192 blocks x 4 waves = 4x oversubscribed
    int gemg = (Nn + 31) / 32;

    // layer 0 (K=9)
    gemm2_mfma_kernel<9><<<gemg, 256, 0, stream>>>(x, Wp, b0l, xlb, xrb, Nn);
    gat_kernel<<<gatg, 256, 0, stream>>>(xlb, xrb, W0e, a0, epi,
                                         rowptr, wstart, csr4, hbuf, nullptr, Nn);
    // 3 residual layers (K=64)
    for (int i = 0; i < 3; i++) {
        gemm2_mfma_kernel<64><<<gemg, 256, 0, stream>>>(
            hbuf, Wp + (size_t)(i + 1) * 32768, bl + (size_t)i * 256, xlb, xrb, Nn);
        gat_kernel<<<gatg, 256, 0, stream>>>(
            xlb, xrb, We + (size_t)i * 768, a + (size_t)i * 256, epi + (size_t)(i + 1) * 128,
            rowptr, wstart, csr4, hbuf, hbuf, Nn);
    }

    // global mean pool + head (fused)
    poolhead_kernel<<<Gg, 256, 0, stream>>>(hbuf, gstart, Wo1, bo1, Wo2, bo2,
                                            (float*)d_out, Gg);
}

// Round 20
// 393.873 us; speedup vs baseline: 1.0340x; 1.0340x over previous
//
#include <hip/hip_runtime.h>
#include <hip/hip_fp16.h>
#include <math.h>

typedef _Float16 h2 __attribute__((ext_vector_type(2)));
typedef _Float16 h8 __attribute__((ext_vector_type(8)));
typedef float f4 __attribute__((ext_vector_type(4)));

#define NWAVES 16384

static __device__ __forceinline__ h2 u2h2(unsigned u) {
    union { unsigned u; h2 h; } x; x.u = u; return x.h;
}

// ---------------------------------------------------------------- CSR build
__global__ __launch_bounds__(256) void count_kernel(const int* __restrict__ dst,
                                                    int* __restrict__ deg, int E) {
    int e = blockIdx.x * 256 + threadIdx.x;
    if (e < E) atomicAdd(&deg[dst[e]], 1);
}

#define SCAN_TPB 256
#define SCAN_VPT 4
#define SCAN_ELEMS (SCAN_TPB * SCAN_VPT)  // 1024

__global__ __launch_bounds__(256) void scan_phase1(const int* __restrict__ deg,
                                                   int* __restrict__ bsum, int n) {
    __shared__ int sh[SCAN_TPB];
    int base = blockIdx.x * SCAN_ELEMS + threadIdx.x * SCAN_VPT;
    int s = 0;
#pragma unroll
    for (int j = 0; j < SCAN_VPT; j++) { int i = base + j; if (i < n) s += deg[i]; }
    sh[threadIdx.x] = s;
    __syncthreads();
    for (int off = 128; off; off >>= 1) {
        if (threadIdx.x < (unsigned)off) sh[threadIdx.x] += sh[threadIdx.x + off];
        __syncthreads();
    }
    if (threadIdx.x == 0) bsum[blockIdx.x] = sh[0];
}

__global__ __launch_bounds__(256) void scan_phase2(int* __restrict__ bsum, int nb,
                                                   int* __restrict__ rowptr, int n) {
    __shared__ int sh[256];
    int v = (threadIdx.x < (unsigned)nb) ? bsum[threadIdx.x] : 0;
    sh[threadIdx.x] = v;
    __syncthreads();
    for (int off = 1; off < 256; off <<= 1) {
        int t = (threadIdx.x >= (unsigned)off) ? sh[threadIdx.x - off] : 0;
        __syncthreads();
        sh[threadIdx.x] += t;
        __syncthreads();
    }
    if (threadIdx.x < (unsigned)nb) bsum[threadIdx.x] = sh[threadIdx.x] - v;  // exclusive
    if (threadIdx.x == 0) rowptr[n] = sh[255];                                // total
}

__global__ __launch_bounds__(256) void scan_phase3(const int* __restrict__ deg,
                                                   const int* __restrict__ bsum,
                                                   int* __restrict__ rowptr,
                                                   int* __restrict__ cursor, int n) {
    __shared__ int sh[SCAN_TPB];
    int tid = threadIdx.x;
    int base = blockIdx.x * SCAN_ELEMS + tid * SCAN_VPT;
    int v[SCAN_VPT];
    int s = 0;
#pragma unroll
    for (int j = 0; j < SCAN_VPT; j++) { int i = base + j; v[j] = (i < n) ? deg[i] : 0; s += v[j]; }
    sh[tid] = s;
    __syncthreads();
    for (int off = 1; off < SCAN_TPB; off <<= 1) {
        int t = (tid >= off) ? sh[tid - off] : 0;
        __syncthreads();
        sh[tid] += t;
        __syncthreads();
    }
    int ex = sh[tid] - s + bsum[blockIdx.x];
#pragma unroll
    for (int j = 0; j < SCAN_VPT; j++) {
        int i = base + j;
        if (i < n) { rowptr[i] = ex; cursor[i] = ex; ex += v[j]; }
    }
}

// CSR record: {src, half2(ea0,ea0), half2(ea1,ea1), half2(ea2,ea2)}
__global__ __launch_bounds__(256) void scatter_kernel(const int* __restrict__ src,
                                                      const int* __restrict__ dst,
                                                      const float* __restrict__ ea,
                                                      int* __restrict__ cursor,
                                                      uint4* __restrict__ csr4, int E) {
    int e = blockIdx.x * 256 + threadIdx.x;
    if (e < E) {
        int d = dst[e];
        int pos = atomicAdd(&cursor[d], 1);
        size_t eb3 = (size_t)e * 3;
        uint4 r;
        r.x = (unsigned)src[e];
        __half2 p0, p1, p2;
        p0.x = p0.y = __float2half_rn(ea[eb3]);
        p1.x = p1.y = __float2half_rn(ea[eb3 + 1]);
        p2.x = p2.y = __float2half_rn(ea[eb3 + 2]);
        r.y = *(unsigned*)&p0; r.z = *(unsigned*)&p1; r.w = *(unsigned*)&p2;
        csr4[pos] = r;
    }
}

// ------------- wave load balance: wstart[q] = first node d whose rowptr[d]
// >= q*E/NWAVES (pure edge balance).
__global__ __launch_bounds__(256) void wbal_kernel(const int* __restrict__ rowptr,
                                                   int Nn, int* __restrict__ wstart) {
    int q = blockIdx.x * 256 + threadIdx.x;
    if (q > NWAVES) return;
    if (q == 0) { wstart[0] = 0; return; }
    if (q == NWAVES) { wstart[NWAVES] = Nn; return; }
    int Etot = rowptr[Nn];
    int t = (int)(((long long)q * Etot) / NWAVES);
    int lo = 0, hi = Nn;
    while (lo < hi) {
        int mid = (lo + hi) >> 1;
        if (rowptr[mid] < t) lo = mid + 1; else hi = mid;
    }
    wstart[q] = lo;
}

// ------------- epilogue constants: A = 0.25*g*rsqrt(v+eps); B = (bias-m)*s+b
__global__ __launch_bounds__(256) void bnprep_kernel(const float* __restrict__ c0,
                                                     const float* __restrict__ cb,   // [3][64]
                                                     const float* __restrict__ bng,
                                                     const float* __restrict__ bnb,
                                                     const float* __restrict__ bnm,
                                                     const float* __restrict__ bnv,
                                                     float* __restrict__ epi) {      // [4][2][64]
    int t = threadIdx.x;           // exactly 256 = 4 layers x 64 channels
    int l = t >> 6, c = t & 63;
    float s = bng[l * 64 + c] * rsqrtf(bnv[l * 64 + c] + 1e-5f);
    float bias = (l == 0) ? c0[c] : cb[(l - 1) * 64 + c];
    epi[l * 128 + c] = 0.25f * s;
    epi[l * 128 + 64 + c] = (bias - bnm[l * 64 + c]) * s + bnb[l * 64 + c];
}

// ------------- group starts from SORTED batch: gstart[g] = first node of g
__global__ __launch_bounds__(256) void gstart_kernel(const int* __restrict__ batch,
                                                     int* __restrict__ gstart,
                                                     int Nn, int Gg) {
    int n = blockIdx.x * 256 + threadIdx.x;
    if (n >= Nn) return;
    int b = batch[n];
    int prev = (n == 0) ? -1 : batch[n - 1];
    for (int g = prev + 1; g <= b; g++) gstart[g] = n;
    if (n == Nn - 1)
        for (int g = b + 1; g <= Gg; g++) gstart[g] = Nn;
}

// ------------- weight prep: pack Wl|Wr (fp16, zero-padded) into MFMA A-frag
__global__ __launch_bounds__(256) void wprep_kernel(const float* __restrict__ W0l,
                                                    const float* __restrict__ W0r,
                                                    const float* __restrict__ Wl,
                                                    const float* __restrict__ Wr,
                                                    __half* __restrict__ Wp) {
    int t = blockIdx.x * 256 + threadIdx.x;   // 4 layers * 4096
    int layer = t >> 12;
    int r = t & 4095;
    int lane = r & 63;
    int ks = (r >> 6) & 1;
    int gct = r >> 7;                          // 0..31
    int K = (layer == 0) ? 9 : 64;
    const float* Wsrc;
    if (layer == 0) Wsrc = (gct < 16) ? W0l : W0r;
    else            Wsrc = ((gct < 16) ? Wl : Wr) + (size_t)(layer - 1) * 64 * 256;
    int cl = ((gct & 15) << 4) + (lane & 15);
    int k0 = (ks << 5) + ((lane >> 4) << 3);
    __half vals[8] __attribute__((aligned(16)));
#pragma unroll
    for (int j = 0; j < 8; j++) {
        int k = k0 + j;
        vals[j] = __float2half_rn((k < K) ? Wsrc[(size_t)k * 256 + cl] : 0.f);
    }
    *(uint4*)(Wp + (size_t)t * 8) = *(const uint4*)vals;
}

// ----------------- MFMA gemm2: xl = fp16(x@Wl+bl), xr = fp16(x@Wr).
template <int K>
__global__ __launch_bounds__(256) void gemm2_mfma_kernel(const float* __restrict__ xin,
                                                         const __half* __restrict__ Wp,
                                                         const float* __restrict__ bl,
                                                         __half* __restrict__ xl,
                                                         __half* __restrict__ xr, int Nn) {
    constexpr int NKS = (K > 32) ? 2 : 1;
    constexpr int KP = NKS * 32;                 // padded K (32 or 64)
    __shared__ __align__(16) float shx[32][KP + 4];
    int tid = threadIdx.x;
    int lane = tid & 63;
    int wv = tid >> 6;           // 0..3
    int nb = blockIdx.x * 32;
    int l15 = lane & 15;
    int lg = lane >> 4;          // 0..3

    // ---- stage B into LDS (coalesced)
    if (K != KP) {
        for (int q = tid; q < 32 * KP; q += 256) shx[q / KP][q % KP] = 0.f;
        __syncthreads();
    }
    if (K == 64) {
        for (int q = tid; q < 32 * 16; q += 256) {   // 512 float4
            int r = q >> 4, c4 = q & 15;
            int node = nb + r;
            float4 v = (node < Nn) ? *(const float4*)(xin + (size_t)node * 64 + c4 * 4)
                                   : make_float4(0.f, 0.f, 0.f, 0.f);
            *(float4*)&shx[r][c4 * 4] = v;
        }
    } else {
        for (int q = tid; q < 32 * K; q += 256) {
            int r = q / K, c = q - r * K;
            int node = nb + r;
            shx[r][c] = (node < Nn) ? xin[(size_t)node * K + c] : 0.f;
        }
    }
    __syncthreads();

    // A fragments (weights), resident: 8 col-tiles x NKS
    h8 afr[8][NKS];
#pragma unroll
    for (int i = 0; i < 8; i++) {
        int gct = wv * 8 + i;
#pragma unroll
        for (int ks = 0; ks < NKS; ks++)
            afr[i][ks] = *(const h8*)(Wp + (((size_t)(gct * 2 + ks)) * 64 + lane) * 8);
    }
    // B fragments from LDS -> fp16
    h8 bfr[2][NKS];
#pragma unroll
    for (int nt = 0; nt < 2; nt++) {
        int row = nt * 16 + l15;
#pragma unroll
        for (int ks = 0; ks < NKS; ks++) {
            int k0 = ks * 32 + lg * 8;
            float4 f0 = *(const float4*)&shx[row][k0];
            float4 f1 = *(const float4*)&shx[row][k0 + 4];
            h8 b;
            b[0] = (_Float16)f0.x; b[1] = (_Float16)f0.y;
            b[2] = (_Float16)f0.z; b[3] = (_Float16)f0.w;
            b[4] = (_Float16)f1.x; b[5] = (_Float16)f1.y;
            b[6] = (_Float16)f1.z; b[7] = (_Float16)f1.w;
            bfr[nt][ks] = b;
        }
    }
    // accumulators, init with bias on the xl side
    f4 acc[8][2];
#pragma unroll
    for (int i = 0; i < 8; i++) {
        int gct = wv * 8 + i;
        f4 ini;
        if (gct < 16) {
            float4 b4 = *(const float4*)(bl + (gct << 4) + (lg << 2));
            ini[0] = b4.x; ini[1] = b4.y; ini[2] = b4.z; ini[3] = b4.w;
        } else {
            ini[0] = 0.f; ini[1] = 0.f; ini[2] = 0.f; ini[3] = 0.f;
        }
        acc[i][0] = ini;
        acc[i][1] = ini;
    }
    // matrix core
#pragma unroll
    for (int i = 0; i < 8; i++)
#pragma unroll
        for (int nt = 0; nt < 2; nt++)
#pragma unroll
            for (int ks = 0; ks < NKS; ks++)
                acc[i][nt] = __builtin_amdgcn_mfma_f32_16x16x32_f16(
                    afr[i][ks], bfr[nt][ks], acc[i][nt], 0, 0, 0);
    // store: 4 consecutive cols per lane -> uint2
#pragma unroll
    for (int i = 0; i < 8; i++) {
        int gct = wv * 8 + i;
        __half* outp = (gct < 16) ? xl : xr;
        int cl = ((gct & 15) << 4) + (lg << 2);
#pragma unroll
        for (int nt = 0; nt < 2; nt++) {
            int node = nb + nt * 16 + l15;
            if (node < Nn) {
                __half h4[4] __attribute__((aligned(8)));
                h4[0] = __float2half_rn(acc[i][nt][0]);
                h4[1] = __float2half_rn(acc[i][nt][1]);
                h4[2] = __float2half_rn(acc[i][nt][2]);
                h4[3] = __float2half_rn(acc[i][nt][3]);
                *(uint2*)(outp + (size_t)node * 256 + cl) = *(const uint2*)h4;
            }
        }
    }
}

// --------------------------- fused GATv2 (R18 final): persistent wave,
// contiguous node ranges, fp16 packed score path, s_load csr4, A/B reg dbuf
// EB=6, 2x oversubscribed grid (block-level backfill absorbs the tail).
#define EB 6

#define GISSUE(S, ibase)                                                               \
    {                                                                                  \
        _Pragma("unroll") for (int j = 0; j < EB; j++) {                               \
            int idx = (ibase) + j;                                                     \
            if (idx < end) {                                                           \
                uint4 ce = csr4[idx]; /* uniform -> s_load_dwordx4 */                  \
                cey##S[j] = ce.y; cez##S[j] = ce.z; cew##S[j] = ce.w;                  \
                int sn = (int)ce.x;                                                    \
                xpk##S[j] = *(const uint2*)(xl + ((size_t)sn << 8) + (lane << 2));     \
            } else {                                                                   \
                cey##S[j] = 0u; cez##S[j] = 0u; cew##S[j] = 0u;                        \
                xpk##S[j] = make_uint2(0u, 0u);                                        \
            }                                                                          \
        }                                                                              \
    }

#define GCOMPUTE(S, ibase)                                                             \
    {                                                                                  \
        float p[EB];                                                                   \
        _Pragma("unroll") for (int j = 0; j < EB; j++) {                               \
            int idx = (ibase) + j;                                                     \
            if (idx < end) {                                                           \
                h2 ea0 = u2h2(cey##S[j]);                                              \
                h2 ea1 = u2h2(cez##S[j]);                                              \
                h2 ea2 = u2h2(cew##S[j]);                                              \
                h2 xl01 = u2h2(xpk##S[j].x);                                           \
                h2 xl23 = u2h2(xpk##S[j].y);                                           \
                h2 t01 = __builtin_elementwise_fma(ea0, we0a,                          \
                           __builtin_elementwise_fma(ea1, we1a,                        \
                             __builtin_elementwise_fma(ea2, we2a, xr01))) + xl01;      \
                h2 t23 = __builtin_elementwise_fma(ea0, we0b,                          \
                           __builtin_elementwise_fma(ea1, we1b,                        \
                             __builtin_elementwise_fma(ea2, we2b, xr23))) + xl23;      \
                h2 l01 = __builtin_elementwise_max(t01, t01 * c02);                    \
                h2 l23 = __builtin_elementwise_max(t23, t23 * c02);                    \
                p[j] = __builtin_amdgcn_fdot2(l01, atta,                               \
                           __builtin_amdgcn_fdot2(l23, attb, 0.f, false), false);      \
            } else p[j] = -INFINITY;                                                   \
        }                                                                              \
        _Pragma("unroll") for (int off = 1; off < 16; off <<= 1) {                     \
            _Pragma("unroll") for (int j = 0; j < EB; j++) p[j] += __shfl_xor(p[j], off); \
        }                                                                              \
        _Pragma("unroll") for (int j = 0; j < EB; j++) {                               \
            float wv2 = __expf(p[j]);                                                  \
            float2 f0 = __half22float2(*(const __half2*)&xpk##S[j].x);                 \
            float2 f1 = __half22float2(*(const __half2*)&xpk##S[j].y);                 \
            f4 xf; xf[0] = f0.x; xf[1] = f0.y; xf[2] = f1.x; xf[3] = f1.y;             \
            acc = acc + wv2 * xf;                                                      \
            l_run += wv2;                                                              \
        }                                                                              \
    }

__global__ __launch_bounds__(256) void gat_kernel(const __half* __restrict__ xl,
                                                  const __half* __restrict__ xr,
                                                  const float* __restrict__ We,   // [3,256]
                                                  const float* __restrict__ att,  // [256]
                                                  const float* __restrict__ epi,  // [2][64]
                                                  const int* __restrict__ rowptr,
                                                  const int* __restrict__ wstart,
                                                  const uint4* __restrict__ csr4,
                                                  float* __restrict__ hout,       // [N,64]
                                                  const float* __restrict__ hres, // [N,64] or null
                                                  int Nn) {
    int tid = threadIdx.x;
    int lane = tid & 63;
    int w = __builtin_amdgcn_readfirstlane(tid >> 6);
    int wave = blockIdx.x * 4 + w;

    // fp16 constants (per-lane)
    float4 we0f = *(const float4*)&We[lane * 4];
    float4 we1f = *(const float4*)&We[256 + lane * 4];
    float4 we2f = *(const float4*)&We[512 + lane * 4];
    float4 attf = *(const float4*)&att[lane * 4];
    h2 we0a = { (_Float16)we0f.x, (_Float16)we0f.y };
    h2 we0b = { (_Float16)we0f.z, (_Float16)we0f.w };
    h2 we1a = { (_Float16)we1f.x, (_Float16)we1f.y };
    h2 we1b = { (_Float16)we1f.z, (_Float16)we1f.w };
    h2 we2a = { (_Float16)we2f.x, (_Float16)we2f.y };
    h2 we2b = { (_Float16)we2f.z, (_Float16)we2f.w };
    h2 atta = { (_Float16)attf.x, (_Float16)attf.y };
    h2 attb = { (_Float16)attf.z, (_Float16)attf.w };
    h2 c02 = { (_Float16)0.2f, (_Float16)0.2f };
    float4 eA = *(const float4*)&epi[(lane & 15) * 4];
    float4 eB4 = *(const float4*)&epi[64 + (lane & 15) * 4];

    int ns = wstart[wave], ne = wstart[wave + 1];
    int d = ns;
    if (d >= ne) return;
    int beg = rowptr[d];            // scalar loads, sequential stream
    int end = rowptr[d + 1];
    uint2 xrp = *(const uint2*)(xr + ((size_t)d << 8) + (lane << 2));

    uint2 xpkA[EB], xpkB[EB];
    unsigned ceyA[EB], cezA[EB], cewA[EB], ceyB[EB], cezB[EB], cewB[EB];

    while (d < ne) {
        // ---- prefetch next node's meta (SGPR + 2 VGPR), consumed at roll
        int dn = d + 1;
        int begn = 0, endn = 0;
        uint2 xrpn = make_uint2(0u, 0u);
        if (dn < ne) {
            begn = rowptr[dn];
            endn = rowptr[dn + 1];
            xrpn = *(const uint2*)(xr + ((size_t)dn << 8) + (lane << 2));
        }
        // ---- current node
        h2 xr01 = u2h2(xrp.x);
        h2 xr23 = u2h2(xrp.y);

        float l_run = 0.f;
        f4 acc; acc[0] = 0.f; acc[1] = 0.f; acc[2] = 0.f; acc[3] = 0.f;

        int i = beg;
        if (i < end) {
            GISSUE(A, i);
            for (;;) {
                int nx = i + EB;
                if (nx < end) GISSUE(B, nx);
                GCOMPUTE(A, i);
                i = nx;
                if (i >= end) break;
                nx = i + EB;
                if (nx < end) GISSUE(A, nx);
                GCOMPUTE(B, i);
                i = nx;
                if (i >= end) break;
            }
        }
        // ---- epilogue: head-mean + BN/bias (precomputed) + ELU + residual
        float inv = (end > beg) ? 1.f / l_run : 0.f;
        float4 o = make_float4(acc[0] * inv, acc[1] * inv, acc[2] * inv, acc[3] * inv);
#pragma unroll
        for (int off = 16; off < 64; off <<= 1) {
            o.x += __shfl_xor(o.x, off);
            o.y += __shfl_xor(o.y, off);
            o.z += __shfl_xor(o.z, off);
            o.w += __shfl_xor(o.w, off);
        }
        if (lane < 16) {
            float vx = fmaf(o.x, eA.x, eB4.x);
            float vy = fmaf(o.y, eA.y, eB4.y);
            float vz = fmaf(o.z, eA.z, eB4.z);
            float vw = fmaf(o.w, eA.w, eB4.w);
            vx = vx > 0.f ? vx : expm1f(vx);
            vy = vy > 0.f ? vy : expm1f(vy);
            vz = vz > 0.f ? vz : expm1f(vz);
            vw = vw > 0.f ? vw : expm1f(vw);
            if (hres) {
                float4 r4 = *(const float4*)&hres[((size_t)d << 6) + (lane << 2)];
                vx += r4.x; vy += r4.y; vz += r4.z; vw += r4.w;
            }
            *(float4*)&hout[((size_t)d << 6) + (lane << 2)] = make_float4(vx, vy, vz, vw);
        }
        // ---- roll to prefetched node
        d = dn; beg = begn; end = endn; xrp = xrpn;
    }
}

// -------------------- pooling + MLP head fused (batch sorted, no atomics)
__global__ __launch_bounds__(256) void poolhead_kernel(const float* __restrict__ h,
                                                       const int* __restrict__ gstart,
                                                       const float* __restrict__ Wo1,
                                                       const float* __restrict__ bo1,
                                                       const float* __restrict__ Wo2,
                                                       const float* __restrict__ bo2,
                                                       float* __restrict__ out, int Gg) {
    __shared__ float red[4][64];
    __shared__ float sp[64];
    int g = blockIdx.x;
    int tid = threadIdx.x;
    int lane = tid & 63, w = tid >> 6;
    int gs = gstart[g], ge = gstart[g + 1];
    float s = 0.f;
    for (int n = gs + w; n < ge; n += 4) s += h[((size_t)n << 6) + lane];
    red[w][lane] = s;
    __syncthreads();
    if (tid < 64) {
        float tot = red[0][tid] + red[1][tid] + red[2][tid] + red[3][tid];
        float c = fmaxf((float)(ge - gs), 1.f);
        sp[tid] = tot / c;
    }
    __syncthreads();
    if (tid < 64) {
        float hid = 0.f;
        if (tid < 32) {
            hid = bo1[tid];
            for (int k = 0; k < 64; k++) hid += sp[k] * Wo1[k * 32 + tid];
            hid = hid > 0.f ? hid : expm1f(hid);
            hid *= Wo2[tid];
        }
#pragma unroll
        for (int off = 32; off; off >>= 1) hid += __shfl_xor(hid, off);
        if (tid == 0) out[g] = hid + bo2[0];
    }
}

extern "C" void kernel_launch(void* const* d_in, const int* in_sizes, int n_in,
                              void* d_out, int out_size, void* d_ws, size_t ws_size,
                              hipStream_t stream) {
    const float* x   = (const float*)d_in[0];
    const int*   ei  = (const int*)d_in[1];
    const int*   bat = (const int*)d_in[2];
    const float* ea  = (const float*)d_in[3];
    const float* W0l = (const float*)d_in[4];
    const float* b0l = (const float*)d_in[5];
    const float* W0r = (const float*)d_in[6];
    const float* W0e = (const float*)d_in[7];
    const float* a0  = (const float*)d_in[8];
    const float* c0  = (const float*)d_in[9];
    const float* Wl  = (const float*)d_in[10];
    const float* bl  = (const float*)d_in[11];
    const float* Wr  = (const float*)d_in[12];
    const float* We  = (const float*)d_in[13];
    const float* a   = (const float*)d_in[14];
    const float* cb  = (const float*)d_in[15];
    const float* bng = (const float*)d_in[16];
    const float* bnb = (const float*)d_in[17];
    const float* bnm = (const float*)d_in[18];
    const float* bnv = (const float*)d_in[19];
    const float* Wo1 = (const float*)d_in[20];
    const float* bo1 = (const float*)d_in[21];
    const float* Wo2 = (const float*)d_in[22];
    const float* bo2 = (const float*)d_in[23];

    int Nn = in_sizes[2];
    int Ee = in_sizes[1] / 2;
    int Gg = out_size;
    const int* srcv = ei;
    const int* dstv = ei + Ee;

    char* w = (char*)d_ws;
    auto alloc = [&](size_t bytes) {
        char* p = w;
        w += (bytes + 255) & ~(size_t)255;
        return p;
    };
    __half* xlb    = (__half*)alloc((size_t)Nn * 256 * 2);
    __half* xrb    = (__half*)alloc((size_t)Nn * 256 * 2);
    float*  hbuf   = (float*)alloc((size_t)Nn * 64 * 4);
    int*    deg    = (int*)alloc((size_t)Nn * 4);
    int*    rowptr = (int*)alloc((size_t)(Nn + 1) * 4);
    int*    cursor = (int*)alloc((size_t)Nn * 4);
    uint4*  csr4   = (uint4*)alloc((size_t)(Ee + 64) * 16);
    int*    gstart = (int*)alloc((size_t)(Gg + 1) * 4);
    int*    wstart = (int*)alloc((size_t)(NWAVES + 1) * 4);
    int*    bsum   = (int*)alloc(256 * 4);
    float*  epi    = (float*)alloc(4 * 128 * 4);
    __half* Wp     = (__half*)alloc((size_t)4 * 32768 * 2);

    int nscan = (Nn + SCAN_ELEMS - 1) / SCAN_ELEMS;  // <=256 for Nn<=262144

    // CSR build + balance + weight/epilogue prep + group starts
    hipMemsetAsync(deg, 0, (size_t)Nn * 4, stream);
    count_kernel<<<(Ee + 255) / 256, 256, 0, stream>>>(dstv, deg, Ee);
    scan_phase1<<<nscan, 256, 0, stream>>>(deg, bsum, Nn);
    scan_phase2<<<1, 256, 0, stream>>>(bsum, nscan, rowptr, Nn);
    scan_phase3<<<nscan, 256, 0, stream>>>(deg, bsum, rowptr, cursor, Nn);
    scatter_kernel<<<(Ee + 255) / 256, 256, 0, stream>>>(srcv, dstv, ea, cursor, csr4, Ee);
    wbal_kernel<<<(NWAVES + 256) / 256, 256, 0, stream>>>(rowptr, Nn, wstart);
    bnprep_kernel<<<1, 256, 0, stream>>>(c0, cb, bng, bnb, bnm, bnv, epi);
    wprep_kernel<<<64, 256, 0, stream>>>(W0l, W0r, Wl, Wr, Wp);
    gstart_kernel<<<(Nn + 255) / 256, 256, 0, stream>>>(bat, gstart, Nn, Gg);

    int gatg = NWAVES / 4;   // 4096 blocks x 4 waves = 2x oversubscribed
    int gemg = (Nn + 31) / 32;

    // layer 0 (K=9)
    gemm2_mfma_kernel<9><<<gemg, 256, 0, stream>>>(x, Wp, b0l, xlb, xrb, Nn);
    gat_kernel<<<gatg, 256, 0, stream>>>(xlb, xrb, W0e, a0, epi,
                                         rowptr, wstart, csr4, hbuf, nullptr, Nn);
    // 3 residual layers (K=64)
    for (int i = 0; i < 3; i++) {
        gemm2_mfma_kernel<64><<<gemg, 256, 0, stream>>>(
            hbuf, Wp + (size_t)(i + 1) * 32768, bl + (size_t)i * 256, xlb, xrb, Nn);
        gat_kernel<<<gatg, 256, 0, stream>>>(
            xlb, xrb, We + (size_t)i * 768, a + (size_t)i * 256, epi + (size_t)(i + 1) * 128,
            rowptr, wstart, csr4, hbuf, hbuf, Nn);
    }

    // global mean pool + head (fused)
    poolhead_kernel<<<Gg, 256, 0, stream>>>(hbuf, gstart, Wo1, bo1, Wo2, bo2,
                                            (float*)d_out, Gg);
}